// Round 1
// 1798.906 us; speedup vs baseline: 1.1303x; 1.1303x over previous
//
#include <hip/hip_runtime.h>
#include <cstdint>
#include <cstddef>

// ---------------- constants ----------------
#define D_  384
#define H_  8
#define HS_ 48
#define L_  8
#define V_  32000
#define B_  32
#define T_  128
#define M_  4096   // B*T

typedef __bf16 bf16;
typedef __bf16 bf16x8 __attribute__((ext_vector_type(8)));
typedef float  floatx4 __attribute__((ext_vector_type(4)));

__device__ __forceinline__ unsigned short bfbits(float f) {
  union { bf16 b; unsigned short u; } cv; cv.b = (bf16)f; return cv.u;
}
__device__ __forceinline__ float bflo(unsigned u) {
  union { float f; unsigned x; } c; c.x = u << 16; return c.f;
}
__device__ __forceinline__ float bfhi(unsigned u) {
  union { float f; unsigned x; } c; c.x = u & 0xffff0000u; return c.f;
}

__device__ __forceinline__ float waveReduceSum(float v) {
  #pragma unroll
  for (int off = 32; off > 0; off >>= 1) v += __shfl_xor(v, off, 64);
  return v;
}

// ---------------- embedding: x = tok_emb[idx] + pos_emb[t]; also bf16 copy ----------------
__global__ void embed_kernel(const int* __restrict__ idx, const float* __restrict__ tok,
                             const float* __restrict__ pos, float* __restrict__ x,
                             bf16* __restrict__ xb) {
  int e = blockIdx.x * 256 + threadIdx.x;       // 0 .. 4096*96-1
  int row = e / 96, c4 = (e % 96) * 4;
  int t = row & (T_ - 1);
  int tk = idx[row];
  const float4 tv = *(const float4*)(tok + (size_t)tk * D_ + c4);
  const float4 pv = *(const float4*)(pos + (size_t)t * D_ + c4);
  float4 o; o.x = tv.x + pv.x; o.y = tv.y + pv.y; o.z = tv.z + pv.z; o.w = tv.w + pv.w;
  *(float4*)(x + (size_t)row * D_ + c4) = o;
  uint2 u;
  u.x = (unsigned)bfbits(o.x) | ((unsigned)bfbits(o.y) << 16);
  u.y = (unsigned)bfbits(o.z) | ((unsigned)bfbits(o.w) << 16);
  *(uint2*)(xb + (size_t)row * D_ + c4) = u;
}

// ---------------- transpose+convert: W [K][N] f32 -> Wt [N][K] bf16 ----------------
__device__ __forceinline__ void transpose_tile(const float* __restrict__ src, bf16* __restrict__ dst,
                                               int K, int N, int k0, int n0) {
  __shared__ float tile[32][33];
  const int r = threadIdx.x >> 5, c = threadIdx.x & 31;
  #pragma unroll
  for (int i = 0; i < 4; i++)
    tile[r + 8*i][c] = src[(size_t)(k0 + r + 8*i) * N + n0 + c];
  __syncthreads();
  #pragma unroll
  for (int i = 0; i < 4; i++)
    dst[(size_t)(n0 + r + 8*i) * K + k0 + c] = (bf16)tile[c][r + 8*i];
}

// one launch per layer: all 6 weight matrices. grid (48, 12, 3), no masked blocks.
__global__ __launch_bounds__(256) void t_layer_kernel(
    const float* __restrict__ Wq, const float* __restrict__ Wk,
    const float* __restrict__ Wv, const float* __restrict__ Wo,
    const float* __restrict__ W1, const float* __restrict__ W2,
    bf16* __restrict__ wqkvoT, bf16* __restrict__ w1t, bf16* __restrict__ w2t) {
  if (blockIdx.z == 0) {
    const int mm = blockIdx.x / 12, nx = blockIdx.x % 12;   // which of QKVO, n-tile
    const float* src = mm == 0 ? Wq : mm == 1 ? Wk : mm == 2 ? Wv : Wo;
    transpose_tile(src, wqkvoT + (size_t)mm * (D_ * D_), D_, D_, blockIdx.y * 32, nx * 32);
  } else if (blockIdx.z == 1) {
    transpose_tile(W1, w1t, D_, 4 * D_, blockIdx.y * 32, blockIdx.x * 32);
  } else {
    transpose_tile(W2, w2t, 4 * D_, D_, blockIdx.x * 32, blockIdx.y * 32);
  }
}

__global__ __launch_bounds__(256) void t_head_kernel(const float* __restrict__ lmW, bf16* __restrict__ dst) {
  transpose_tile(lmW, dst, D_, V_, blockIdx.y * 32, blockIdx.x * 32);
}

// ---------------- GEMM: C[M][N] = A[M][K](bf16) @ Bt[N][K]^T(bf16), fp32 acc ----------------
// 128x128 block tile, 4 waves 2x2, BK=32, mfma_f32_16x16x32_bf16.
// LDS rows padded to 56 bf16 (112B = 7*16B): 16B-aligned b128, 2-way bank aliasing (free).
template<bool BIAS, bool RESID, bool RELU, bool OUTBF>
__device__ __forceinline__ void gemm_core(
    const bf16* __restrict__ A, const bf16* __restrict__ Bt,
    const float* __restrict__ bias, const float* __restrict__ resid,
    void* __restrict__ Cout, int N, int K, int m0, int n0)
{
  __shared__ bf16 As[128][56];
  __shared__ bf16 Bs[128][56];
  const int tid  = threadIdx.x;
  const int lane = tid & 63;
  const int wave = tid >> 6;
  const int wr = wave >> 1, wc = wave & 1;
  const int lrow = lane & 15, quad = lane >> 4;

  floatx4 acc[4][4];
  #pragma unroll
  for (int i = 0; i < 4; i++)
    #pragma unroll
    for (int j = 0; j < 4; j++) acc[i][j] = floatx4{0.f, 0.f, 0.f, 0.f};

  const int r0 = tid >> 2,          p0 = (tid & 3) * 8;
  const int r1 = (tid + 256) >> 2,  p1 = p0;   // (tid+256)&3 == tid&3

  for (int k0 = 0; k0 < K; k0 += 32) {
    __syncthreads();
    const uint4 a0 = *(const uint4*)(A  + (size_t)(m0 + r0) * K + k0 + p0);
    const uint4 a1 = *(const uint4*)(A  + (size_t)(m0 + r1) * K + k0 + p1);
    const uint4 b0 = *(const uint4*)(Bt + (size_t)(n0 + r0) * K + k0 + p0);
    const uint4 b1 = *(const uint4*)(Bt + (size_t)(n0 + r1) * K + k0 + p1);
    *(uint4*)&As[r0][p0] = a0;
    *(uint4*)&As[r1][p1] = a1;
    *(uint4*)&Bs[r0][p0] = b0;
    *(uint4*)&Bs[r1][p1] = b1;
    __syncthreads();
    bf16x8 af[4], bfr[4];
    #pragma unroll
    for (int mt = 0; mt < 4; mt++) af[mt]  = *(const bf16x8*)&As[wr*64 + mt*16 + lrow][quad*8];
    #pragma unroll
    for (int nt = 0; nt < 4; nt++) bfr[nt] = *(const bf16x8*)&Bs[wc*64 + nt*16 + lrow][quad*8];
    #pragma unroll
    for (int mt = 0; mt < 4; mt++)
      #pragma unroll
      for (int nt = 0; nt < 4; nt++)
        acc[mt][nt] = __builtin_amdgcn_mfma_f32_16x16x32_bf16(af[mt], bfr[nt], acc[mt][nt], 0, 0, 0);
  }

  #pragma unroll
  for (int mt = 0; mt < 4; mt++) {
    #pragma unroll
    for (int nt = 0; nt < 4; nt++) {
      const int col = n0 + wc*64 + nt*16 + lrow;
      float bv = 0.f;
      if (BIAS) bv = bias[col];
      #pragma unroll
      for (int i = 0; i < 4; i++) {
        const int row = m0 + wr*64 + mt*16 + quad*4 + i;
        float vv = acc[mt][nt][i] + bv;
        if (RESID) vv += resid[(size_t)row * N + col];
        if (RELU)  vv = vv > 0.f ? vv : 0.f;
        if (OUTBF) ((bf16*)Cout)[(size_t)row * N + col] = (bf16)vv;
        else       ((float*)Cout)[(size_t)row * N + col] = vv;
      }
    }
  }
}

template<bool BIAS, bool RESID, bool RELU, bool OUTBF>
__global__ __launch_bounds__(256) void gemm_kernel(const bf16* __restrict__ A, const bf16* __restrict__ Bt,
    const float* __restrict__ bias, const float* __restrict__ resid, void* __restrict__ C, int N, int K) {
  gemm_core<BIAS, RESID, RELU, OUTBF>(A, Bt, bias, resid, C, N, K, blockIdx.x * 128, blockIdx.y * 128);
}

// q/k/v now produced directly in bf16 (halves qkv HBM traffic, frees ws for weight staging)
__global__ __launch_bounds__(256) void gemm_qkv_kernel(const bf16* __restrict__ A, const bf16* __restrict__ Wt,
    bf16* __restrict__ q, bf16* __restrict__ k, bf16* __restrict__ v) {
  const bf16* Bt = Wt + (size_t)blockIdx.z * (D_ * D_);
  bf16* C = blockIdx.z == 0 ? q : (blockIdx.z == 1 ? k : v);
  gemm_core<false, false, false, true>(A, Bt, nullptr, nullptr, C, D_, D_, blockIdx.x * 128, blockIdx.y * 128);
}

// ---------------- attention: per (b,h), 4 threads per query row (12 dims each) ----------------
// 512 threads = 8 waves (vs old 2): per-wave serial chain per key column drops from
// 24 ds_read_b128 + ~100 VALU to 3 ds_read_b128 + ~30 VALU; dot combined via shfl_xor.
__global__ __launch_bounds__(512) void attn_kernel(const bf16* __restrict__ q,
    const bf16* __restrict__ k, const bf16* __restrict__ v, bf16* __restrict__ attnb) {
  __shared__ float ks[T_][48];
  __shared__ float vs[T_][48];
  const int bh = blockIdx.x;
  const int b = bh >> 3, h = bh & 7;
  const int r  = threadIdx.x >> 2;   // query row 0..127
  const int qq = threadIdx.x & 3;    // quarter of head dim
  const int o  = qq * 12;
  const size_t rowbase = ((size_t)(b * T_ + r)) * D_ + h * HS_ + o;
  float qr[12];
  #pragma unroll
  for (int j = 0; j < 3; j++) {
    const uint2 tk = *(const uint2*)(k + rowbase + 4*j);
    const uint2 tv = *(const uint2*)(v + rowbase + 4*j);
    const uint2 tq = *(const uint2*)(q + rowbase + 4*j);
    float4 fk, fv;
    fk.x = bflo(tk.x); fk.y = bfhi(tk.x); fk.z = bflo(tk.y); fk.w = bfhi(tk.y);
    fv.x = bflo(tv.x); fv.y = bfhi(tv.x); fv.z = bflo(tv.y); fv.w = bfhi(tv.y);
    *(float4*)&ks[r][o + 4*j] = fk;
    *(float4*)&vs[r][o + 4*j] = fv;
    qr[4*j]   = bflo(tq.x); qr[4*j+1] = bfhi(tq.x);
    qr[4*j+2] = bflo(tq.y); qr[4*j+3] = bfhi(tq.y);
  }
  __syncthreads();
  float m = -3.0e38f, l = 0.f, acc[12];
  #pragma unroll
  for (int j = 0; j < 12; j++) acc[j] = 0.f;
  const float scale = 0.14433756729740643f;   // 48^-0.5
  for (int c = 0; c < T_; c++) {
    float s = 0.f;
    #pragma unroll
    for (int j = 0; j < 12; j++) s += qr[j] * ks[c][o + j];
    s += __shfl_xor(s, 1, 64);
    s += __shfl_xor(s, 2, 64);
    s *= scale;
    if (c > r) s = -3.0e38f;                    // causal mask
    const float mn = fmaxf(m, s);
    const float al = __expf(m - mn);
    const float pp = __expf(s - mn);
    l = l * al + pp;
    #pragma unroll
    for (int j = 0; j < 12; j++) acc[j] = acc[j] * al + pp * vs[c][o + j];
    m = mn;
  }
  const float inv = 1.f / l;
  unsigned ob[6];
  #pragma unroll
  for (int j = 0; j < 6; j++)
    ob[j] = (unsigned)bfbits(acc[2*j] * inv) | ((unsigned)bfbits(acc[2*j+1] * inv) << 16);
  bf16* dst = attnb + rowbase;
  #pragma unroll
  for (int j = 0; j < 3; j++) {
    uint2 u; u.x = ob[2*j]; u.y = ob[2*j+1];
    *(uint2*)(dst + 4*j) = u;
  }
}

// ---------------- LayerNorm: one wave per row, D=384 = 64 lanes x 6 ----------------
__global__ __launch_bounds__(256) void ln_kernel(const float* __restrict__ in,
    const float* __restrict__ g, const float* __restrict__ bta,
    float* __restrict__ xo, bf16* __restrict__ xbo) {
  const int wave = threadIdx.x >> 6, lane = threadIdx.x & 63;
  const int row = blockIdx.x * 4 + wave;
  const float* p = in + (size_t)row * D_;
  float v[6];
  #pragma unroll
  for (int j = 0; j < 6; j++) v[j] = p[lane + 64*j];
  float s = 0.f;
  #pragma unroll
  for (int j = 0; j < 6; j++) s += v[j];
  s = waveReduceSum(s);
  const float mean = s * (1.f / 384.f);
  float qv = 0.f;
  #pragma unroll
  for (int j = 0; j < 6; j++) { v[j] -= mean; qv += v[j] * v[j]; }
  qv = waveReduceSum(qv);
  const float rs = rsqrtf(qv * (1.f / 384.f) + 1e-5f);
  #pragma unroll
  for (int j = 0; j < 6; j++) {
    const int c = lane + 64*j;
    const float o = v[j] * rs * g[c] + bta[c];
    xo[(size_t)row * D_ + c]  = o;
    xbo[(size_t)row * D_ + c] = (bf16)o;
  }
}

// ---------------- driver ----------------
extern "C" void kernel_launch(void* const* d_in, const int* in_sizes, int n_in,
                              void* d_out, int out_size, void* d_ws, size_t ws_size,
                              hipStream_t stream) {
  const int*   index = (const int*)  d_in[0];
  const float* tok   = (const float*)d_in[1];
  const float* pos   = (const float*)d_in[2];
  const float* Wq    = (const float*)d_in[3];
  const float* Wk    = (const float*)d_in[4];
  const float* Wv    = (const float*)d_in[5];
  const float* Wo    = (const float*)d_in[6];
  const float* bo    = (const float*)d_in[7];
  const float* W1    = (const float*)d_in[8];
  const float* b1    = (const float*)d_in[9];
  const float* W2    = (const float*)d_in[10];
  const float* b2    = (const float*)d_in[11];
  const float* ln1g  = (const float*)d_in[12];
  const float* ln1b  = (const float*)d_in[13];
  const float* ln2g  = (const float*)d_in[14];
  const float* ln2b  = (const float*)d_in[15];
  const float* lnfg  = (const float*)d_in[16];
  const float* lnfb  = (const float*)d_in[17];
  const float* lmW   = (const float*)d_in[18];
  const float* lmb   = (const float*)d_in[19];
  float* out = (float*)d_out;
  char* ws = (char*)d_ws;

  // ws layout (48 MiB). bf16 q/k/v freed 9.4 MB -> dedicated transposed-weight regions
  // (no lifetime aliasing; all 6 per-layer transposes run in ONE launch at layer start).
  float* x     = (float*)(ws + 0);          // 6.29 MB fp32 residual stream
  float* tmp   = (float*)(ws + 6291456);    // 6.29 MB fp32 pre-LN sums
  bf16*  xb    = (bf16*) (ws + 12582912);   // 3.15 MB bf16 copy of x
  bf16*  qb    = (bf16*) (ws + 15728640);   // 3.15 MB bf16
  bf16*  kb    = (bf16*) (ws + 18874368);   // 3.15 MB bf16
  bf16*  vb    = (bf16*) (ws + 22020096);   // 3.15 MB bf16
  bf16*  attnb = (bf16*) (ws + 25165824);   // 3.15 MB bf16 attention output
  bf16*  hb    = (bf16*) (ws + 28311552);   // 12.58 MB bf16 FFN hidden (ends 40894464)
  bf16*  wqkvoT= (bf16*) (ws + 40894464);   // 1.18 MB: 4x 384x384 bf16
  bf16*  w1t   = (bf16*) (ws + 42074112);   // 1.18 MB
  bf16*  w2t   = (bf16*) (ws + 43253760);   // 1.18 MB (ends 44433408 < 50331648)
  bf16*  lmT   = (bf16*) (ws + 15728640);   // qb..hb span: all dead at head time (24.6 MB)

  embed_kernel<<<1536, 256, 0, stream>>>(index, tok, pos, x, xb);
  for (int l = 0; l < L_; l++) {
    t_layer_kernel<<<dim3(48, 12, 3), 256, 0, stream>>>(
        Wq + (size_t)l * D_ * D_, Wk + (size_t)l * D_ * D_,
        Wv + (size_t)l * D_ * D_, Wo + (size_t)l * D_ * D_,
        W1 + (size_t)l * D_ * 4 * D_, W2 + (size_t)l * 4 * D_ * D_,
        wqkvoT, w1t, w2t);
    gemm_qkv_kernel<<<dim3(32, 3, 3), 256, 0, stream>>>(xb, wqkvoT, qb, kb, vb);
    attn_kernel<<<256, 512, 0, stream>>>(qb, kb, vb, attnb);
    gemm_kernel<true, true, false, false><<<dim3(32, 3), 256, 0, stream>>>(
        attnb, wqkvoT + 3 * D_ * D_, bo + l * D_, x, tmp, D_, D_);
    ln_kernel<<<1024, 256, 0, stream>>>(tmp, ln1g + l * D_, ln1b + l * D_, x, xb);
    gemm_kernel<true, false, true, true><<<dim3(32, 12), 256, 0, stream>>>(
        xb, w1t, b1 + l * 4 * D_, nullptr, hb, 4 * D_, D_);
    gemm_kernel<true, true, false, false><<<dim3(32, 3), 256, 0, stream>>>(
        hb, w2t, b2 + l * D_, x, tmp, D_, 4 * D_);
    ln_kernel<<<1024, 256, 0, stream>>>(tmp, ln2g + l * D_, ln2b + l * D_, x, xb);
  }
  ln_kernel<<<1024, 256, 0, stream>>>(x, lnfg, lnfb, x, xb);
  t_head_kernel<<<dim3(1000, 12), 256, 0, stream>>>(lmW, lmT);
  gemm_kernel<true, false, false, false><<<dim3(32, 250), 256, 0, stream>>>(
      xb, lmT, lmb, nullptr, out, V_, D_);
}

// Round 2
// 1655.451 us; speedup vs baseline: 1.2283x; 1.0867x over previous
//
#include <hip/hip_runtime.h>
#include <cstdint>
#include <cstddef>

// ---------------- constants ----------------
#define D_  384
#define H_  8
#define HS_ 48
#define L_  8
#define V_  32000
#define B_  32
#define T_  128
#define M_  4096   // B*T

typedef __bf16 bf16;
typedef __bf16 bf16x8 __attribute__((ext_vector_type(8)));
typedef float  floatx4 __attribute__((ext_vector_type(4)));

__device__ __forceinline__ unsigned short bfbits(float f) {
  union { bf16 b; unsigned short u; } cv; cv.b = (bf16)f; return cv.u;
}
__device__ __forceinline__ float bflo(unsigned u) {
  union { float f; unsigned x; } c; c.x = u << 16; return c.f;
}
__device__ __forceinline__ float bfhi(unsigned u) {
  union { float f; unsigned x; } c; c.x = u & 0xffff0000u; return c.f;
}

__device__ __forceinline__ float waveReduceSum(float v) {
  #pragma unroll
  for (int off = 32; off > 0; off >>= 1) v += __shfl_xor(v, off, 64);
  return v;
}

// async global->LDS, 16B per lane. LDS dest = wave-uniform base + lane*16.
__device__ __forceinline__ void gload_lds16(const void* g, void* l) {
  __builtin_amdgcn_global_load_lds(
      (const __attribute__((address_space(1))) void*)g,
      (__attribute__((address_space(3))) void*)l, 16, 0, 0);
}

// ---------------- embedding: x = tok_emb[idx] + pos_emb[t]; also bf16 copy ----------------
__global__ void embed_kernel(const int* __restrict__ idx, const float* __restrict__ tok,
                             const float* __restrict__ pos, float* __restrict__ x,
                             bf16* __restrict__ xb) {
  int e = blockIdx.x * 256 + threadIdx.x;       // 0 .. 4096*96-1
  int row = e / 96, c4 = (e % 96) * 4;
  int t = row & (T_ - 1);
  int tk = idx[row];
  const float4 tv = *(const float4*)(tok + (size_t)tk * D_ + c4);
  const float4 pv = *(const float4*)(pos + (size_t)t * D_ + c4);
  float4 o; o.x = tv.x + pv.x; o.y = tv.y + pv.y; o.z = tv.z + pv.z; o.w = tv.w + pv.w;
  *(float4*)(x + (size_t)row * D_ + c4) = o;
  uint2 u;
  u.x = (unsigned)bfbits(o.x) | ((unsigned)bfbits(o.y) << 16);
  u.y = (unsigned)bfbits(o.z) | ((unsigned)bfbits(o.w) << 16);
  *(uint2*)(xb + (size_t)row * D_ + c4) = u;
}

// ---------------- transpose+convert: W [K][N] f32 -> Wt [N][K] bf16 ----------------
__device__ __forceinline__ void transpose_tile(const float* __restrict__ src, bf16* __restrict__ dst,
                                               int K, int N, int k0, int n0) {
  __shared__ float tile[32][33];
  const int r = threadIdx.x >> 5, c = threadIdx.x & 31;
  #pragma unroll
  for (int i = 0; i < 4; i++)
    tile[r + 8*i][c] = src[(size_t)(k0 + r + 8*i) * N + n0 + c];
  __syncthreads();
  #pragma unroll
  for (int i = 0; i < 4; i++)
    dst[(size_t)(n0 + r + 8*i) * K + k0 + c] = (bf16)tile[c][r + 8*i];
}

// one launch per layer: all 6 weight matrices. grid (48, 12, 3), no masked blocks.
__global__ __launch_bounds__(256) void t_layer_kernel(
    const float* __restrict__ Wq, const float* __restrict__ Wk,
    const float* __restrict__ Wv, const float* __restrict__ Wo,
    const float* __restrict__ W1, const float* __restrict__ W2,
    bf16* __restrict__ wqkvoT, bf16* __restrict__ w1t, bf16* __restrict__ w2t) {
  if (blockIdx.z == 0) {
    const int mm = blockIdx.x / 12, nx = blockIdx.x % 12;   // which of QKVO, n-tile
    const float* src = mm == 0 ? Wq : mm == 1 ? Wk : mm == 2 ? Wv : Wo;
    transpose_tile(src, wqkvoT + (size_t)mm * (D_ * D_), D_, D_, blockIdx.y * 32, nx * 32);
  } else if (blockIdx.z == 1) {
    transpose_tile(W1, w1t, D_, 4 * D_, blockIdx.y * 32, blockIdx.x * 32);
  } else {
    transpose_tile(W2, w2t, 4 * D_, D_, blockIdx.x * 32, blockIdx.y * 32);
  }
}

__global__ __launch_bounds__(256) void t_head_kernel(const float* __restrict__ lmW, bf16* __restrict__ dst) {
  transpose_tile(lmW, dst, D_, V_, blockIdx.y * 32, blockIdx.x * 32);
}

// ---------------- GEMM: C[M][N] = A[M][K](bf16) @ Bt[N][K]^T(bf16), fp32 acc ----------------
// BMx128 block tile, 4 waves 2x2 (each wave (BM/2)x64), BK=32, mfma_f32_16x16x32_bf16.
// Staging via global_load_lds width=16 (m97 structure). LDS linear rows of 32 bf16 (64B);
// bank spread via XOR swizzle: physical 16B-slot = logical_slot ^ ((row>>1)&3),
// applied on BOTH sides: pre-swizzled per-lane GLOBAL source addr + swizzled ds_read addr.
template<int BM, bool BIAS, bool RESID, bool RELU, bool OUTBF>
__device__ __forceinline__ void gemm_core(
    const bf16* __restrict__ A, const bf16* __restrict__ Bt,
    const float* __restrict__ bias, const float* __restrict__ resid,
    void* __restrict__ Cout, int N, int K, int m0, int n0)
{
  constexpr int MTC = BM / 32;           // m-fragments per wave (4 or 2)
  __shared__ bf16 As[BM * 32];
  __shared__ bf16 Bs[128 * 32];
  const int tid  = threadIdx.x;
  const int lane = tid & 63;
  const int wave = tid >> 6;
  const int wr = wave >> 1, wc = wave & 1;
  const int lrow = lane & 15, quad = lane >> 4;
  const int rdoff = ((quad ^ ((lrow >> 1) & 3)) << 3);   // swizzled bf16 col within row

  // staging geometry: one call stages 16 rows x 64B; lane -> (row=lane>>2, slot=lane&3).
  // source col pre-swizzle: slot_log = (lane&3) ^ ((row>>1)&3) = (lane&3) ^ ((lane>>3)&3).
  const int srow = lane >> 2;
  const int scol = (((lane & 3) ^ ((lane >> 3) & 3)) << 3);

  floatx4 acc[MTC][4];
  #pragma unroll
  for (int i = 0; i < MTC; i++)
    #pragma unroll
    for (int j = 0; j < 4; j++) acc[i][j] = floatx4{0.f, 0.f, 0.f, 0.f};

  const bf16* gA = A  + (size_t)(m0 + wave * (BM / 4) + srow) * K + scol;
  const bf16* gB = Bt + (size_t)(n0 + wave * 32       + srow) * K + scol;
  bf16* lA = As + wave * (BM * 8);     // BM*32/4 bf16 per-wave chunk
  bf16* lB = Bs + wave * 1024;

  for (int k0 = 0; k0 < K; k0 += 32) {
    #pragma unroll
    for (int j = 0; j < BM / 64; j++)
      gload_lds16(gA + k0 + (size_t)j * 16 * K, lA + j * 512);
    #pragma unroll
    for (int j = 0; j < 2; j++)
      gload_lds16(gB + k0 + (size_t)j * 16 * K, lB + j * 512);
    __syncthreads();   // drains vmcnt(0): staged data visible
    bf16x8 af[MTC], bfr[4];
    #pragma unroll
    for (int mt = 0; mt < MTC; mt++)
      af[mt]  = *(const bf16x8*)&As[(wr * (BM / 2) + mt * 16 + lrow) * 32 + rdoff];
    #pragma unroll
    for (int nt = 0; nt < 4; nt++)
      bfr[nt] = *(const bf16x8*)&Bs[(wc * 64 + nt * 16 + lrow) * 32 + rdoff];
    #pragma unroll
    for (int mt = 0; mt < MTC; mt++)
      #pragma unroll
      for (int nt = 0; nt < 4; nt++)
        acc[mt][nt] = __builtin_amdgcn_mfma_f32_16x16x32_bf16(af[mt], bfr[nt], acc[mt][nt], 0, 0, 0);
    __syncthreads();   // protect LDS from next iteration's staging
  }

  #pragma unroll
  for (int mt = 0; mt < MTC; mt++) {
    #pragma unroll
    for (int nt = 0; nt < 4; nt++) {
      const int col = n0 + wc * 64 + nt * 16 + lrow;
      float bv = 0.f;
      if (BIAS) bv = bias[col];
      #pragma unroll
      for (int i = 0; i < 4; i++) {
        const int row = m0 + wr * (BM / 2) + mt * 16 + quad * 4 + i;
        float vv = acc[mt][nt][i] + bv;
        if (RESID) vv += resid[(size_t)row * N + col];
        if (RELU)  vv = vv > 0.f ? vv : 0.f;
        if (OUTBF) ((bf16*)Cout)[(size_t)row * N + col] = (bf16)vv;
        else       ((float*)Cout)[(size_t)row * N + col] = vv;
      }
    }
  }
}

template<int BM, bool BIAS, bool RESID, bool RELU, bool OUTBF>
__global__ __launch_bounds__(256) void gemm_kernel(const bf16* __restrict__ A, const bf16* __restrict__ Bt,
    const float* __restrict__ bias, const float* __restrict__ resid, void* __restrict__ C, int N, int K) {
  gemm_core<BM, BIAS, RESID, RELU, OUTBF>(A, Bt, bias, resid, C, N, K, blockIdx.x * BM, blockIdx.y * 128);
}

// q/k/v produced directly in bf16
__global__ __launch_bounds__(256) void gemm_qkv_kernel(const bf16* __restrict__ A, const bf16* __restrict__ Wt,
    bf16* __restrict__ q, bf16* __restrict__ k, bf16* __restrict__ v) {
  const bf16* Bt = Wt + (size_t)blockIdx.z * (D_ * D_);
  bf16* C = blockIdx.z == 0 ? q : (blockIdx.z == 1 ? k : v);
  gemm_core<128, false, false, false, true>(A, Bt, nullptr, nullptr, C, D_, D_, blockIdx.x * 128, blockIdx.y * 128);
}

// ---------------- attention: per (b,h), 4 threads per query row (12 dims each) ----------------
__global__ __launch_bounds__(512) void attn_kernel(const bf16* __restrict__ q,
    const bf16* __restrict__ k, const bf16* __restrict__ v, bf16* __restrict__ attnb) {
  __shared__ float ks[T_][48];
  __shared__ float vs[T_][48];
  const int bh = blockIdx.x;
  const int b = bh >> 3, h = bh & 7;
  const int r  = threadIdx.x >> 2;   // query row 0..127
  const int qq = threadIdx.x & 3;    // quarter of head dim
  const int o  = qq * 12;
  const size_t rowbase = ((size_t)(b * T_ + r)) * D_ + h * HS_ + o;
  float qr[12];
  #pragma unroll
  for (int j = 0; j < 3; j++) {
    const uint2 tk = *(const uint2*)(k + rowbase + 4*j);
    const uint2 tv = *(const uint2*)(v + rowbase + 4*j);
    const uint2 tq = *(const uint2*)(q + rowbase + 4*j);
    float4 fk, fv;
    fk.x = bflo(tk.x); fk.y = bfhi(tk.x); fk.z = bflo(tk.y); fk.w = bfhi(tk.y);
    fv.x = bflo(tv.x); fv.y = bfhi(tv.x); fv.z = bflo(tv.y); fv.w = bfhi(tv.y);
    *(float4*)&ks[r][o + 4*j] = fk;
    *(float4*)&vs[r][o + 4*j] = fv;
    qr[4*j]   = bflo(tq.x); qr[4*j+1] = bfhi(tq.x);
    qr[4*j+2] = bflo(tq.y); qr[4*j+3] = bfhi(tq.y);
  }
  __syncthreads();
  float m = -3.0e38f, l = 0.f, acc[12];
  #pragma unroll
  for (int j = 0; j < 12; j++) acc[j] = 0.f;
  const float scale = 0.14433756729740643f;   // 48^-0.5
  for (int c = 0; c < T_; c++) {
    float s = 0.f;
    #pragma unroll
    for (int j = 0; j < 12; j++) s += qr[j] * ks[c][o + j];
    s += __shfl_xor(s, 1, 64);
    s += __shfl_xor(s, 2, 64);
    s *= scale;
    if (c > r) s = -3.0e38f;                    // causal mask
    const float mn = fmaxf(m, s);
    const float al = __expf(m - mn);
    const float pp = __expf(s - mn);
    l = l * al + pp;
    #pragma unroll
    for (int j = 0; j < 12; j++) acc[j] = acc[j] * al + pp * vs[c][o + j];
    m = mn;
  }
  const float inv = 1.f / l;
  unsigned ob[6];
  #pragma unroll
  for (int j = 0; j < 6; j++)
    ob[j] = (unsigned)bfbits(acc[2*j] * inv) | ((unsigned)bfbits(acc[2*j+1] * inv) << 16);
  bf16* dst = attnb + rowbase;
  #pragma unroll
  for (int j = 0; j < 3; j++) {
    uint2 u; u.x = ob[2*j]; u.y = ob[2*j+1];
    *(uint2*)(dst + 4*j) = u;
  }
}

// ---------------- LayerNorm: one wave per row, D=384 = 64 lanes x 6 ----------------
__global__ __launch_bounds__(256) void ln_kernel(const float* __restrict__ in,
    const float* __restrict__ g, const float* __restrict__ bta,
    float* __restrict__ xo, bf16* __restrict__ xbo) {
  const int wave = threadIdx.x >> 6, lane = threadIdx.x & 63;
  const int row = blockIdx.x * 4 + wave;
  const float* p = in + (size_t)row * D_;
  float v[6];
  #pragma unroll
  for (int j = 0; j < 6; j++) v[j] = p[lane + 64*j];
  float s = 0.f;
  #pragma unroll
  for (int j = 0; j < 6; j++) s += v[j];
  s = waveReduceSum(s);
  const float mean = s * (1.f / 384.f);
  float qv = 0.f;
  #pragma unroll
  for (int j = 0; j < 6; j++) { v[j] -= mean; qv += v[j] * v[j]; }
  qv = waveReduceSum(qv);
  const float rs = rsqrtf(qv * (1.f / 384.f) + 1e-5f);
  #pragma unroll
  for (int j = 0; j < 6; j++) {
    const int c = lane + 64*j;
    const float o = v[j] * rs * g[c] + bta[c];
    xo[(size_t)row * D_ + c]  = o;
    xbo[(size_t)row * D_ + c] = (bf16)o;
  }
}

// ---------------- driver ----------------
extern "C" void kernel_launch(void* const* d_in, const int* in_sizes, int n_in,
                              void* d_out, int out_size, void* d_ws, size_t ws_size,
                              hipStream_t stream) {
  const int*   index = (const int*)  d_in[0];
  const float* tok   = (const float*)d_in[1];
  const float* pos   = (const float*)d_in[2];
  const float* Wq    = (const float*)d_in[3];
  const float* Wk    = (const float*)d_in[4];
  const float* Wv    = (const float*)d_in[5];
  const float* Wo    = (const float*)d_in[6];
  const float* bo    = (const float*)d_in[7];
  const float* W1    = (const float*)d_in[8];
  const float* b1    = (const float*)d_in[9];
  const float* W2    = (const float*)d_in[10];
  const float* b2    = (const float*)d_in[11];
  const float* ln1g  = (const float*)d_in[12];
  const float* ln1b  = (const float*)d_in[13];
  const float* ln2g  = (const float*)d_in[14];
  const float* ln2b  = (const float*)d_in[15];
  const float* lnfg  = (const float*)d_in[16];
  const float* lnfb  = (const float*)d_in[17];
  const float* lmW   = (const float*)d_in[18];
  const float* lmb   = (const float*)d_in[19];
  float* out = (float*)d_out;
  char* ws = (char*)d_ws;

  float* x     = (float*)(ws + 0);          // 6.29 MB fp32 residual stream
  float* tmp   = (float*)(ws + 6291456);    // 6.29 MB fp32 pre-LN sums
  bf16*  xb    = (bf16*) (ws + 12582912);   // 3.15 MB bf16 copy of x
  bf16*  qb    = (bf16*) (ws + 15728640);   // 3.15 MB bf16
  bf16*  kb    = (bf16*) (ws + 18874368);   // 3.15 MB bf16
  bf16*  vb    = (bf16*) (ws + 22020096);   // 3.15 MB bf16
  bf16*  attnb = (bf16*) (ws + 25165824);   // 3.15 MB bf16 attention output
  bf16*  hb    = (bf16*) (ws + 28311552);   // 12.58 MB bf16 FFN hidden (ends 40894464)
  bf16*  wqkvoT= (bf16*) (ws + 40894464);   // 1.18 MB: 4x 384x384 bf16
  bf16*  w1t   = (bf16*) (ws + 42074112);   // 1.18 MB
  bf16*  w2t   = (bf16*) (ws + 43253760);   // 1.18 MB (ends 44433408 < 50331648)
  bf16*  lmT   = (bf16*) (ws + 15728640);   // qb..hb span: all dead at head time (24.6 MB)

  embed_kernel<<<1536, 256, 0, stream>>>(index, tok, pos, x, xb);
  for (int l = 0; l < L_; l++) {
    t_layer_kernel<<<dim3(48, 12, 3), 256, 0, stream>>>(
        Wq + (size_t)l * D_ * D_, Wk + (size_t)l * D_ * D_,
        Wv + (size_t)l * D_ * D_, Wo + (size_t)l * D_ * D_,
        W1 + (size_t)l * D_ * 4 * D_, W2 + (size_t)l * 4 * D_ * D_,
        wqkvoT, w1t, w2t);
    gemm_qkv_kernel<<<dim3(32, 3, 3), 256, 0, stream>>>(xb, wqkvoT, qb, kb, vb);
    attn_kernel<<<256, 512, 0, stream>>>(qb, kb, vb, attnb);
    // Wo: BM=64 -> grid (64,3)=192 blocks (was 96)
    gemm_kernel<64, true, true, false, false><<<dim3(64, 3), 256, 0, stream>>>(
        attnb, wqkvoT + 3 * D_ * D_, bo + l * D_, x, tmp, D_, D_);
    ln_kernel<<<1024, 256, 0, stream>>>(tmp, ln1g + l * D_, ln1b + l * D_, x, xb);
    gemm_kernel<128, true, false, true, true><<<dim3(32, 12), 256, 0, stream>>>(
        xb, w1t, b1 + l * 4 * D_, nullptr, hb, 4 * D_, D_);
    // FFN2: BM=64 -> grid (64,3)=192 blocks (was 96), K=1536
    gemm_kernel<64, true, true, false, false><<<dim3(64, 3), 256, 0, stream>>>(
        hb, w2t, b2 + l * D_, x, tmp, D_, 4 * D_);
    ln_kernel<<<1024, 256, 0, stream>>>(tmp, ln2g + l * D_, ln2b + l * D_, x, xb);
  }
  ln_kernel<<<1024, 256, 0, stream>>>(x, lnfg, lnfb, x, xb);
  t_head_kernel<<<dim3(1000, 12), 256, 0, stream>>>(lmW, lmT);
  gemm_kernel<128, true, false, false, false><<<dim3(32, 250), 256, 0, stream>>>(
      xb, lmT, lmb, nullptr, out, V_, D_);
}

// Round 3
// 1635.437 us; speedup vs baseline: 1.2433x; 1.0122x over previous
//
#include <hip/hip_runtime.h>
#include <cstdint>
#include <cstddef>

// ---------------- constants ----------------
#define D_  384
#define H_  8
#define HS_ 48
#define L_  8
#define V_  32000
#define B_  32
#define T_  128
#define M_  4096   // B*T

typedef __bf16 bf16;
typedef __bf16 bf16x8 __attribute__((ext_vector_type(8)));
typedef float  floatx4 __attribute__((ext_vector_type(4)));

__device__ __forceinline__ unsigned short bfbits(float f) {
  union { bf16 b; unsigned short u; } cv; cv.b = (bf16)f; return cv.u;
}
__device__ __forceinline__ float bflo(unsigned u) {
  union { float f; unsigned x; } c; c.x = u << 16; return c.f;
}
__device__ __forceinline__ float bfhi(unsigned u) {
  union { float f; unsigned x; } c; c.x = u & 0xffff0000u; return c.f;
}

__device__ __forceinline__ float waveReduceSum(float v) {
  #pragma unroll
  for (int off = 32; off > 0; off >>= 1) v += __shfl_xor(v, off, 64);
  return v;
}

// async global->LDS, 16B per lane. LDS dest = wave-uniform base + lane*16.
__device__ __forceinline__ void gload_lds16(const void* g, void* l) {
  __builtin_amdgcn_global_load_lds(
      (const __attribute__((address_space(1))) void*)g,
      (__attribute__((address_space(3))) void*)l, 16, 0, 0);
}

// ---------------- embedding: x = tok_emb[idx] + pos_emb[t]; also bf16 copy ----------------
__global__ void embed_kernel(const int* __restrict__ idx, const float* __restrict__ tok,
                             const float* __restrict__ pos, float* __restrict__ x,
                             bf16* __restrict__ xb) {
  int e = blockIdx.x * 256 + threadIdx.x;       // 0 .. 4096*96-1
  int row = e / 96, c4 = (e % 96) * 4;
  int t = row & (T_ - 1);
  int tk = idx[row];
  const float4 tv = *(const float4*)(tok + (size_t)tk * D_ + c4);
  const float4 pv = *(const float4*)(pos + (size_t)t * D_ + c4);
  float4 o; o.x = tv.x + pv.x; o.y = tv.y + pv.y; o.z = tv.z + pv.z; o.w = tv.w + pv.w;
  *(float4*)(x + (size_t)row * D_ + c4) = o;
  uint2 u;
  u.x = (unsigned)bfbits(o.x) | ((unsigned)bfbits(o.y) << 16);
  u.y = (unsigned)bfbits(o.z) | ((unsigned)bfbits(o.w) << 16);
  *(uint2*)(xb + (size_t)row * D_ + c4) = u;
}

// ---------------- transpose+convert: W [K][N] f32 -> Wt [N][K] bf16 ----------------
__device__ __forceinline__ void transpose_tile(const float* __restrict__ src, bf16* __restrict__ dst,
                                               int K, int N, int k0, int n0) {
  __shared__ float tile[32][33];
  const int r = threadIdx.x >> 5, c = threadIdx.x & 31;
  #pragma unroll
  for (int i = 0; i < 4; i++)
    tile[r + 8*i][c] = src[(size_t)(k0 + r + 8*i) * N + n0 + c];
  __syncthreads();
  #pragma unroll
  for (int i = 0; i < 4; i++)
    dst[(size_t)(n0 + r + 8*i) * K + k0 + c] = (bf16)tile[c][r + 8*i];
}

// one launch per layer: all 6 weight matrices. grid (48, 12, 3), no masked blocks.
__global__ __launch_bounds__(256) void t_layer_kernel(
    const float* __restrict__ Wq, const float* __restrict__ Wk,
    const float* __restrict__ Wv, const float* __restrict__ Wo,
    const float* __restrict__ W1, const float* __restrict__ W2,
    bf16* __restrict__ wqkvoT, bf16* __restrict__ w1t, bf16* __restrict__ w2t) {
  if (blockIdx.z == 0) {
    const int mm = blockIdx.x / 12, nx = blockIdx.x % 12;   // which of QKVO, n-tile
    const float* src = mm == 0 ? Wq : mm == 1 ? Wk : mm == 2 ? Wv : Wo;
    transpose_tile(src, wqkvoT + (size_t)mm * (D_ * D_), D_, D_, blockIdx.y * 32, nx * 32);
  } else if (blockIdx.z == 1) {
    transpose_tile(W1, w1t, D_, 4 * D_, blockIdx.y * 32, blockIdx.x * 32);
  } else {
    transpose_tile(W2, w2t, 4 * D_, D_, blockIdx.x * 32, blockIdx.y * 32);
  }
}

__global__ __launch_bounds__(256) void t_head_kernel(const float* __restrict__ lmW, bf16* __restrict__ dst) {
  transpose_tile(lmW, dst, D_, V_, blockIdx.y * 32, blockIdx.x * 32);
}

// ---------------- GEMM: C[M][N] = A[M][K](bf16) @ Bt[N][K]^T(bf16), fp32 acc ----------------
// BMx128 block tile, 4 waves 2x2 (each wave (BM/2)x64), BK=32, mfma_f32_16x16x32_bf16.
// T3-minimum 2-phase pipeline: double-buffered LDS; STAGE(t+1) issued BEFORE compute(t);
// ONE __syncthreads per K-step (its implicit vmcnt(0)+lgkmcnt(0) drain is the prefetch
// wait AND the read-before-overwrite guard).
// Staging via global_load_lds width=16. LDS linear rows of 32 bf16 (64B); bank spread via
// XOR swizzle: physical 16B-slot = logical_slot ^ ((row>>1)&3), applied on BOTH sides:
// pre-swizzled per-lane GLOBAL source addr + swizzled ds_read addr.
template<int BM, bool BIAS, bool RESID, bool RELU, bool OUTBF>
__device__ __forceinline__ void gemm_core(
    const bf16* __restrict__ A, const bf16* __restrict__ Bt,
    const float* __restrict__ bias, const float* __restrict__ resid,
    void* __restrict__ Cout, int N, int K, int m0, int n0)
{
  constexpr int MTC = BM / 32;           // m-fragments per wave (4 or 2)
  __shared__ bf16 As[2][BM * 32];
  __shared__ bf16 Bs[2][128 * 32];
  const int tid  = threadIdx.x;
  const int lane = tid & 63;
  const int wave = tid >> 6;
  const int wr = wave >> 1, wc = wave & 1;
  const int lrow = lane & 15, quad = lane >> 4;
  const int rdoff = ((quad ^ ((lrow >> 1) & 3)) << 3);   // swizzled bf16 col within row

  // staging geometry: one call stages 16 rows x 64B; lane -> (row=lane>>2, slot=lane&3).
  // source col pre-swizzle: slot_log = (lane&3) ^ ((row>>1)&3) = (lane&3) ^ ((lane>>3)&3).
  const int srow = lane >> 2;
  const int scol = (((lane & 3) ^ ((lane >> 3) & 3)) << 3);

  floatx4 acc[MTC][4];
  #pragma unroll
  for (int i = 0; i < MTC; i++)
    #pragma unroll
    for (int j = 0; j < 4; j++) acc[i][j] = floatx4{0.f, 0.f, 0.f, 0.f};

  const bf16* gA = A  + (size_t)(m0 + wave * (BM / 4) + srow) * K + scol;
  const bf16* gB = Bt + (size_t)(n0 + wave * 32       + srow) * K + scol;

  auto STAGE = [&](int buf, int kk) {
    bf16* lA = &As[buf][wave * (BM * 8)];   // BM*32/4 bf16 per-wave chunk
    bf16* lB = &Bs[buf][wave * 1024];
    #pragma unroll
    for (int j = 0; j < BM / 64; j++)
      gload_lds16(gA + kk + (size_t)j * 16 * K, lA + j * 512);
    #pragma unroll
    for (int j = 0; j < 2; j++)
      gload_lds16(gB + kk + (size_t)j * 16 * K, lB + j * 512);
  };

  STAGE(0, 0);
  __syncthreads();                         // prologue drain: tile 0 visible
  int cur = 0;
  for (int k0 = 0; k0 < K; k0 += 32) {
    if (k0 + 32 < K) STAGE(cur ^ 1, k0 + 32);   // prefetch next tile (stays in flight)
    bf16x8 af[MTC], bfr[4];
    #pragma unroll
    for (int mt = 0; mt < MTC; mt++)
      af[mt]  = *(const bf16x8*)&As[cur][(wr * (BM / 2) + mt * 16 + lrow) * 32 + rdoff];
    #pragma unroll
    for (int nt = 0; nt < 4; nt++)
      bfr[nt] = *(const bf16x8*)&Bs[cur][(wc * 64 + nt * 16 + lrow) * 32 + rdoff];
    #pragma unroll
    for (int mt = 0; mt < MTC; mt++)
      #pragma unroll
      for (int nt = 0; nt < 4; nt++)
        acc[mt][nt] = __builtin_amdgcn_mfma_f32_16x16x32_bf16(af[mt], bfr[nt], acc[mt][nt], 0, 0, 0);
    __syncthreads();   // drains prefetch (vmcnt 0) + guards buf reuse; ONE barrier/K-step
    cur ^= 1;
  }

  #pragma unroll
  for (int mt = 0; mt < MTC; mt++) {
    #pragma unroll
    for (int nt = 0; nt < 4; nt++) {
      const int col = n0 + wc * 64 + nt * 16 + lrow;
      float bv = 0.f;
      if (BIAS) bv = bias[col];
      #pragma unroll
      for (int i = 0; i < 4; i++) {
        const int row = m0 + wr * (BM / 2) + mt * 16 + quad * 4 + i;
        float vv = acc[mt][nt][i] + bv;
        if (RESID) vv += resid[(size_t)row * N + col];
        if (RELU)  vv = vv > 0.f ? vv : 0.f;
        if (OUTBF) ((bf16*)Cout)[(size_t)row * N + col] = (bf16)vv;
        else       ((float*)Cout)[(size_t)row * N + col] = vv;
      }
    }
  }
}

template<int BM, bool BIAS, bool RESID, bool RELU, bool OUTBF>
__global__ __launch_bounds__(256) void gemm_kernel(const bf16* __restrict__ A, const bf16* __restrict__ Bt,
    const float* __restrict__ bias, const float* __restrict__ resid, void* __restrict__ C, int N, int K) {
  gemm_core<BM, BIAS, RESID, RELU, OUTBF>(A, Bt, bias, resid, C, N, K, blockIdx.x * BM, blockIdx.y * 128);
}

// q/k/v produced directly in bf16
__global__ __launch_bounds__(256) void gemm_qkv_kernel(const bf16* __restrict__ A, const bf16* __restrict__ Wt,
    bf16* __restrict__ q, bf16* __restrict__ k, bf16* __restrict__ v) {
  const bf16* Bt = Wt + (size_t)blockIdx.z * (D_ * D_);
  bf16* C = blockIdx.z == 0 ? q : (blockIdx.z == 1 ? k : v);
  gemm_core<128, false, false, false, true>(A, Bt, nullptr, nullptr, C, D_, D_, blockIdx.x * 128, blockIdx.y * 128);
}

// ---------------- attention: per (b,h), 4 threads per query row (12 dims each) ----------------
__global__ __launch_bounds__(512) void attn_kernel(const bf16* __restrict__ q,
    const bf16* __restrict__ k, const bf16* __restrict__ v, bf16* __restrict__ attnb) {
  __shared__ float ks[T_][48];
  __shared__ float vs[T_][48];
  const int bh = blockIdx.x;
  const int b = bh >> 3, h = bh & 7;
  const int r  = threadIdx.x >> 2;   // query row 0..127
  const int qq = threadIdx.x & 3;    // quarter of head dim
  const int o  = qq * 12;
  const size_t rowbase = ((size_t)(b * T_ + r)) * D_ + h * HS_ + o;
  float qr[12];
  #pragma unroll
  for (int j = 0; j < 3; j++) {
    const uint2 tk = *(const uint2*)(k + rowbase + 4*j);
    const uint2 tv = *(const uint2*)(v + rowbase + 4*j);
    const uint2 tq = *(const uint2*)(q + rowbase + 4*j);
    float4 fk, fv;
    fk.x = bflo(tk.x); fk.y = bfhi(tk.x); fk.z = bflo(tk.y); fk.w = bfhi(tk.y);
    fv.x = bflo(tv.x); fv.y = bfhi(tv.x); fv.z = bflo(tv.y); fv.w = bfhi(tv.y);
    *(float4*)&ks[r][o + 4*j] = fk;
    *(float4*)&vs[r][o + 4*j] = fv;
    qr[4*j]   = bflo(tq.x); qr[4*j+1] = bfhi(tq.x);
    qr[4*j+2] = bflo(tq.y); qr[4*j+3] = bfhi(tq.y);
  }
  __syncthreads();
  float m = -3.0e38f, l = 0.f, acc[12];
  #pragma unroll
  for (int j = 0; j < 12; j++) acc[j] = 0.f;
  const float scale = 0.14433756729740643f;   // 48^-0.5
  for (int c = 0; c < T_; c++) {
    float s = 0.f;
    #pragma unroll
    for (int j = 0; j < 12; j++) s += qr[j] * ks[c][o + j];
    s += __shfl_xor(s, 1, 64);
    s += __shfl_xor(s, 2, 64);
    s *= scale;
    if (c > r) s = -3.0e38f;                    // causal mask
    const float mn = fmaxf(m, s);
    const float al = __expf(m - mn);
    const float pp = __expf(s - mn);
    l = l * al + pp;
    #pragma unroll
    for (int j = 0; j < 12; j++) acc[j] = acc[j] * al + pp * vs[c][o + j];
    m = mn;
  }
  const float inv = 1.f / l;
  unsigned ob[6];
  #pragma unroll
  for (int j = 0; j < 6; j++)
    ob[j] = (unsigned)bfbits(acc[2*j] * inv) | ((unsigned)bfbits(acc[2*j+1] * inv) << 16);
  bf16* dst = attnb + rowbase;
  #pragma unroll
  for (int j = 0; j < 3; j++) {
    uint2 u; u.x = ob[2*j]; u.y = ob[2*j+1];
    *(uint2*)(dst + 4*j) = u;
  }
}

// ---------------- LayerNorm: one wave per row, D=384 = 64 lanes x 6 ----------------
__global__ __launch_bounds__(256) void ln_kernel(const float* __restrict__ in,
    const float* __restrict__ g, const float* __restrict__ bta,
    float* __restrict__ xo, bf16* __restrict__ xbo) {
  const int wave = threadIdx.x >> 6, lane = threadIdx.x & 63;
  const int row = blockIdx.x * 4 + wave;
  const float* p = in + (size_t)row * D_;
  float v[6];
  #pragma unroll
  for (int j = 0; j < 6; j++) v[j] = p[lane + 64*j];
  float s = 0.f;
  #pragma unroll
  for (int j = 0; j < 6; j++) s += v[j];
  s = waveReduceSum(s);
  const float mean = s * (1.f / 384.f);
  float qv = 0.f;
  #pragma unroll
  for (int j = 0; j < 6; j++) { v[j] -= mean; qv += v[j] * v[j]; }
  qv = waveReduceSum(qv);
  const float rs = rsqrtf(qv * (1.f / 384.f) + 1e-5f);
  #pragma unroll
  for (int j = 0; j < 6; j++) {
    const int c = lane + 64*j;
    const float o = v[j] * rs * g[c] + bta[c];
    xo[(size_t)row * D_ + c]  = o;
    xbo[(size_t)row * D_ + c] = (bf16)o;
  }
}

// ---------------- driver ----------------
extern "C" void kernel_launch(void* const* d_in, const int* in_sizes, int n_in,
                              void* d_out, int out_size, void* d_ws, size_t ws_size,
                              hipStream_t stream) {
  const int*   index = (const int*)  d_in[0];
  const float* tok   = (const float*)d_in[1];
  const float* pos   = (const float*)d_in[2];
  const float* Wq    = (const float*)d_in[3];
  const float* Wk    = (const float*)d_in[4];
  const float* Wv    = (const float*)d_in[5];
  const float* Wo    = (const float*)d_in[6];
  const float* bo    = (const float*)d_in[7];
  const float* W1    = (const float*)d_in[8];
  const float* b1    = (const float*)d_in[9];
  const float* W2    = (const float*)d_in[10];
  const float* b2    = (const float*)d_in[11];
  const float* ln1g  = (const float*)d_in[12];
  const float* ln1b  = (const float*)d_in[13];
  const float* ln2g  = (const float*)d_in[14];
  const float* ln2b  = (const float*)d_in[15];
  const float* lnfg  = (const float*)d_in[16];
  const float* lnfb  = (const float*)d_in[17];
  const float* lmW   = (const float*)d_in[18];
  const float* lmb   = (const float*)d_in[19];
  float* out = (float*)d_out;
  char* ws = (char*)d_ws;

  float* x     = (float*)(ws + 0);          // 6.29 MB fp32 residual stream
  float* tmp   = (float*)(ws + 6291456);    // 6.29 MB fp32 pre-LN sums
  bf16*  xb    = (bf16*) (ws + 12582912);   // 3.15 MB bf16 copy of x
  bf16*  qb    = (bf16*) (ws + 15728640);   // 3.15 MB bf16
  bf16*  kb    = (bf16*) (ws + 18874368);   // 3.15 MB bf16
  bf16*  vb    = (bf16*) (ws + 22020096);   // 3.15 MB bf16
  bf16*  attnb = (bf16*) (ws + 25165824);   // 3.15 MB bf16 attention output
  bf16*  hb    = (bf16*) (ws + 28311552);   // 12.58 MB bf16 FFN hidden (ends 40894464)
  bf16*  wqkvoT= (bf16*) (ws + 40894464);   // 1.18 MB: 4x 384x384 bf16
  bf16*  w1t   = (bf16*) (ws + 42074112);   // 1.18 MB
  bf16*  w2t   = (bf16*) (ws + 43253760);   // 1.18 MB (ends 44433408 < 50331648)
  bf16*  lmT   = (bf16*) (ws + 15728640);   // qb..hb span: all dead at head time (24.6 MB)

  embed_kernel<<<1536, 256, 0, stream>>>(index, tok, pos, x, xb);
  for (int l = 0; l < L_; l++) {
    t_layer_kernel<<<dim3(48, 12, 3), 256, 0, stream>>>(
        Wq + (size_t)l * D_ * D_, Wk + (size_t)l * D_ * D_,
        Wv + (size_t)l * D_ * D_, Wo + (size_t)l * D_ * D_,
        W1 + (size_t)l * D_ * 4 * D_, W2 + (size_t)l * 4 * D_ * D_,
        wqkvoT, w1t, w2t);
    gemm_qkv_kernel<<<dim3(32, 3, 3), 256, 0, stream>>>(xb, wqkvoT, qb, kb, vb);
    attn_kernel<<<256, 512, 0, stream>>>(qb, kb, vb, attnb);
    // Wo: BM=64 -> grid (64,3)=192 blocks
    gemm_kernel<64, true, true, false, false><<<dim3(64, 3), 256, 0, stream>>>(
        attnb, wqkvoT + 3 * D_ * D_, bo + l * D_, x, tmp, D_, D_);
    ln_kernel<<<1024, 256, 0, stream>>>(tmp, ln1g + l * D_, ln1b + l * D_, x, xb);
    gemm_kernel<128, true, false, true, true><<<dim3(32, 12), 256, 0, stream>>>(
        xb, w1t, b1 + l * 4 * D_, nullptr, hb, 4 * D_, D_);
    // FFN2: BM=64 -> grid (64,3)=192 blocks, K=1536
    gemm_kernel<64, true, true, false, false><<<dim3(64, 3), 256, 0, stream>>>(
        hb, w2t, b2 + l * D_, x, tmp, D_, 4 * D_);
    ln_kernel<<<1024, 256, 0, stream>>>(tmp, ln2g + l * D_, ln2b + l * D_, x, xb);
  }
  ln_kernel<<<1024, 256, 0, stream>>>(x, lnfg, lnfb, x, xb);
  t_head_kernel<<<dim3(1000, 12), 256, 0, stream>>>(lmW, lmT);
  gemm_kernel<128, true, false, false, false><<<dim3(32, 250), 256, 0, stream>>>(
      xb, lmT, lmb, nullptr, out, V_, D_);
}